// Round 2
// baseline (114.862 us; speedup 1.0000x reference)
//
#include <hip/hip_runtime.h>
#include <stdint.h>

// ScatterND (k=1): out = data.copy(); out[indices[i]] = updates[i]
// data:    [1000000, 64] f32   indices: [100000, 1] i32   updates: [100000, 64] f32
//
// 3-dispatch plan (all memory-bound, stream-ordered):
//   1. zero_flags: clear 1-byte-per-row flag array in d_ws (1 MB)
//   2. scatter_flag: write update rows into out, set flag[idx[i]] = 1
//   3. copy_skip: copy data rows into out where flag==0  (saves re-reading +
//      double-writing the 100k scattered rows: ~51 MB less traffic than
//      copy-everything-then-scatter)

__global__ void zero_bytes_kernel(uint4* __restrict__ p, size_t n16) {
    size_t i = (size_t)blockIdx.x * blockDim.x + threadIdx.x;
    const size_t stride = (size_t)gridDim.x * blockDim.x;
    for (; i < n16; i += stride) p[i] = make_uint4(0u, 0u, 0u, 0u);
}

__global__ void scatter_flag_kernel(const int* __restrict__ idx,
                                    const float4* __restrict__ upd,
                                    float4* __restrict__ out,
                                    uint8_t* __restrict__ flags,
                                    size_t total4) {
    // Thread i handles float4 #(i&15) of update-row #(i>>4).
    size_t i = (size_t)blockIdx.x * blockDim.x + threadIdx.x;
    const size_t stride = (size_t)gridDim.x * blockDim.x;
    for (; i < total4; i += stride) {
        const size_t row = i >> 4;
        const size_t col = i & 15;
        const int r = idx[row];
        out[(size_t)r * 16 + col] = upd[i];
        if (col == 0) flags[r] = 1;
    }
}

__global__ void copy_skip_kernel(const float4* __restrict__ src,
                                 float4* __restrict__ dst,
                                 const uint8_t* __restrict__ flags,
                                 size_t n4) {
    const size_t stride = (size_t)gridDim.x * blockDim.x;
    size_t i = (size_t)blockIdx.x * blockDim.x + threadIdx.x;
    // 4x unrolled: 4 independent loads in flight before stores (MLP).
    for (; i + 3 * stride < n4; i += 4 * stride) {
        const size_t i0 = i, i1 = i + stride, i2 = i + 2 * stride, i3 = i + 3 * stride;
        const bool c0 = !flags[i0 >> 4];
        const bool c1 = !flags[i1 >> 4];
        const bool c2 = !flags[i2 >> 4];
        const bool c3 = !flags[i3 >> 4];
        float4 v0, v1, v2, v3;
        if (c0) v0 = src[i0];
        if (c1) v1 = src[i1];
        if (c2) v2 = src[i2];
        if (c3) v3 = src[i3];
        if (c0) dst[i0] = v0;
        if (c1) dst[i1] = v1;
        if (c2) dst[i2] = v2;
        if (c3) dst[i3] = v3;
    }
    for (; i < n4; i += stride) {
        if (!flags[i >> 4]) dst[i] = src[i];
    }
}

// Fallback (ws too small): plain copy then scatter.
__global__ void copy_all_kernel(const float4* __restrict__ src,
                                float4* __restrict__ dst, size_t n4) {
    size_t i = (size_t)blockIdx.x * blockDim.x + threadIdx.x;
    const size_t stride = (size_t)gridDim.x * blockDim.x;
    for (; i < n4; i += stride) dst[i] = src[i];
}

__global__ void scatter_kernel(const int* __restrict__ idx,
                               const float4* __restrict__ upd,
                               float4* __restrict__ out, size_t total4) {
    size_t i = (size_t)blockIdx.x * blockDim.x + threadIdx.x;
    const size_t stride = (size_t)gridDim.x * blockDim.x;
    for (; i < total4; i += stride) {
        const size_t row = i >> 4;
        const size_t col = i & 15;
        const int r = idx[row];
        out[(size_t)r * 16 + col] = upd[i];
    }
}

extern "C" void kernel_launch(void* const* d_in, const int* in_sizes, int n_in,
                              void* d_out, int out_size, void* d_ws, size_t ws_size,
                              hipStream_t stream) {
    const float* data    = (const float*)d_in[0];
    const int*   indices = (const int*)d_in[1];
    const float* updates = (const float*)d_in[2];
    float* out = (float*)d_out;

    const size_t n4          = (size_t)out_size / 4;       // float4 count of out
    const size_t num_rows    = (size_t)out_size / 64;      // 1,000,000
    const size_t num_updates = (size_t)in_sizes[2] / 64;   // 100,000
    const size_t total4      = num_updates * 16;

    const int block = 256;
    auto grid_for = [&](size_t work) {
        size_t g = (work + block - 1) / block;
        if (g > 2048) g = 2048;
        return (int)g;
    };

    if (ws_size >= num_rows && (num_rows % 16) == 0) {
        uint8_t* flags = (uint8_t*)d_ws;
        const size_t n16 = num_rows / 16;
        zero_bytes_kernel<<<grid_for(n16), block, 0, stream>>>((uint4*)d_ws, n16);
        scatter_flag_kernel<<<grid_for(total4), block, 0, stream>>>(
            indices, (const float4*)updates, (float4*)out, flags, total4);
        copy_skip_kernel<<<grid_for(n4 / 4), block, 0, stream>>>(
            (const float4*)data, (float4*)out, flags, n4);
    } else {
        copy_all_kernel<<<grid_for(n4), block, 0, stream>>>(
            (const float4*)data, (float4*)out, n4);
        scatter_kernel<<<grid_for(total4), block, 0, stream>>>(
            indices, (const float4*)updates, (float4*)out, total4);
    }
}